// Round 11
// baseline (317.136 us; speedup 1.0000x reference)
//
#include <hip/hip_runtime.h>

// ELKUNet forward on MI355X — round 11. f32 device tensors (proven r1/r2/r4/r5).
// r10 lesson: mega1 (scatter||pre1||pre2) got VGPR_Count=40 — merged-role
// regalloc budgeted for the cheap branch, sinking BOTH weight arrays to
// per-iteration reloads (3rd residency failure; VGPR_Count is the tell).
// Fix: merge only ISOMORPHIC roles. k_prew = pre1||pre2 (identical structure:
// one 64-float weight array, one matvec, one store; wave-uniform role branch)
// with __launch_bounds__(256,4) -> VGPR cap 128 > ~95 needed. Scatter back to
// its own kernel. mega2 (seg||nbr) + k_final (unroll 4) kept from r10.

typedef unsigned int u32;
typedef unsigned long long u64;

#define EPSV 1e-6f
#define HBITS 19
#define HSIZE (1u << HBITS)
#define HMASK (HSIZE - 1u)

template<int C,int R> __device__ __forceinline__ float dpp_add(float x){
    int y = __builtin_amdgcn_update_dpp(0, __float_as_int(x), C, R, 0xf, true);
    return x + __int_as_float(y);
}
// full 64-lane sum broadcast to all lanes; pure VALU + 1 readlane.
__device__ __forceinline__ float wave_sum(float x){
    x = dpp_add<0xB1,0xF>(x);   // xor 1
    x = dpp_add<0x4E,0xF>(x);   // xor 2
    x = dpp_add<0x141,0xF>(x);  // xor 4
    x = dpp_add<0x140,0xF>(x);  // xor 8
    x = dpp_add<0x142,0xA>(x);  // row_bcast:15
    x = dpp_add<0x143,0xC>(x);  // row_bcast:31
    return __int_as_float(__builtin_amdgcn_readlane(__float_as_int(x), 63));
}

__device__ __forceinline__ u32 hslot(u32 b){ return (b * 0x9E3779B1u) >> (32 - HBITS); }

__global__ void k_scatter(const int* __restrict__ coords, u64* __restrict__ hash,
                          u32* __restrict__ bm, int n){
    int i = blockIdx.x * blockDim.x + threadIdx.x;
    if(i < n){
        int4 c = ((const int4*)coords)[i];
        u32 b = ((u32)c.x << 16) | ((u32)c.y << 8) | (u32)c.z;
        atomicOr(&bm[b >> 5], 1u << (b & 31));
        u64 entry = ((u64)b << 32) | (u32)i;
        u32 s = hslot(b);
        while(atomicCAS(&hash[s], ~0ull, entry) != ~0ull) s = (s + 1) & HMASK;
    }
}

// pre1 || pre2 with uniform structure: blocks [0,pBlocks) = pre1 (W_pre row
// layout, +LN, ->F_input); blocks [pBlocks,2*pBlocks) = pre2 (conv_w[13]
// column layout, plain sum, ->selfconv). One resident 64-float array either way.
__launch_bounds__(256, 4)
__global__ void k_prew(const float* __restrict__ feats, const float* __restrict__ W_pre,
                       const float* __restrict__ conv_w,
                       const float* __restrict__ lnw, const float* __restrict__ lnb,
                       float* __restrict__ F_input, float* __restrict__ selfconv,
                       int n, int pBlocks){
    const int lane = threadIdx.x & 63;
    const bool isLN = (int)blockIdx.x < pBlocks;
    const int nwaves = pBlocks * 4;
    const int wave = (isLN ? blockIdx.x : blockIdx.x - pBlocks) * 4 + (threadIdx.x >> 6);

    float W[64];
    if(isLN){
        const float4* wr = (const float4*)(W_pre + (size_t)lane * 64);
#pragma unroll
        for(int q = 0; q < 16; ++q){
            float4 v = wr[q];
            W[4*q] = v.x; W[4*q+1] = v.y; W[4*q+2] = v.z; W[4*q+3] = v.w;
        }
    } else {
#pragma unroll
        for(int j = 0; j < 64; ++j) W[j] = conv_w[(13*64 + j)*64 + lane];
    }
    const float lw = isLN ? lnw[lane] : 0.f;
    const float lb = isLN ? lnb[lane] : 0.f;
    float* __restrict__ outp = isLN ? F_input : selfconv;

    for(int i = wave; i < n; i += nwaves){
        const int si = __builtin_amdgcn_readfirstlane(i);
        const float4* fr = (const float4*)(feats + (size_t)si * 64);
        float a0=0.f, a1=0.f, a2=0.f, a3=0.f;
#pragma unroll
        for(int q = 0; q < 16; ++q){
            float4 f = fr[q];
            a0 = fmaf(f.x, W[4*q],   a0);
            a1 = fmaf(f.y, W[4*q+1], a1);
            a2 = fmaf(f.z, W[4*q+2], a2);
            a3 = fmaf(f.w, W[4*q+3], a3);
        }
        float acc = (a0 + a1) + (a2 + a3);
        if(isLN){
            float m = wave_sum(acc) * (1.f/64.f);
            float t = acc - m;
            float v = wave_sum(t*t) * (1.f/64.f);
            acc = t * rsqrtf(v + EPSV) * lw + lb;
        }
        outp[(size_t)si*64 + lane] = acc;
    }
}

// ---- mega2: seg || nbr (r10 verbatim) ------------------------------------
__launch_bounds__(256)
__global__ void mega2(const float* __restrict__ F_input,
                      const float* __restrict__ W_pos, const float* __restrict__ alpha,
                      const int* __restrict__ coords,
                      const u64* __restrict__ hash, const u32* __restrict__ bm,
                      float* __restrict__ sums, float* __restrict__ counts,
                      u32* __restrict__ nbrcnt, u32* __restrict__ nbrlst,
                      int n, int segBlocks){
    const int b = blockIdx.x;
    const int lane = threadIdx.x & 63;

    if(b < segBlocks){                                 // ---- seg ----
        const u64* bm64 = (const u64*)bm;
        const int seg  = (b << 2) + (threadIdx.x >> 6);
        const int cx = seg >> 10, cy = (seg >> 5) & 31, cz = seg & 31;
        const int px = (cx << 3) + (lane >> 3), py = (cy << 3) + (lane & 7);
        u64 w = bm64[((size_t)px << 10) | ((u32)py << 2) | (u32)(cz >> 3)];
        u32 o8 = (u32)(w >> ((cz & 7) * 8)) & 0xffu;
        float cnt = wave_sum((float)__popc(o8));

        const float wx = W_pos[lane*3+0], wy = W_pos[lane*3+1], wz = W_pos[lane*3+2];
        const float al = alpha[lane];
        float aC = 0.f, aS = 0.f, aL = 0.f;
        while(__ballot(o8 != 0u)){
            int myz = 0, pid = -1;
            if(o8){
                int dz = __ffs(o8) - 1; o8 &= o8 - 1;
                myz = (cz << 3) + dz;
                u32 bb = ((u32)px << 16) | ((u32)py << 8) | (u32)myz;
                u32 s = hslot(bb); u64 e;
                while((u32)((e = hash[s]) >> 32) != bb) s = (s + 1) & HMASK;
                pid = (int)(u32)e;
            }
            u64 mm = __ballot(pid >= 0);
            while(mm){
                int l = __ffsll(mm) - 1; mm &= mm - 1;
                int p  = __builtin_amdgcn_readlane(pid, l);
                int pz = __builtin_amdgcn_readlane(myz, l);
                int qx = (cx << 3) + (l >> 3), qy = (cy << 3) + (l & 7);
                float F = F_input[(size_t)p * 64 + lane];
                float pos = ((float)qx*wx + (float)qy*wy + (float)pz*wz) * al;
                aC = fmaf(F, __cosf(pos), aC);
                aS = fmaf(F, __sinf(pos), aS);
                aL = fmaf(F, pos, aL);
            }
        }
        float* sp = sums + (size_t)seg * 192;
        sp[lane] = aC; sp[64 + lane] = aS; sp[128 + lane] = aL;
        if(lane == 0) counts[seg] = cnt;
        return;
    }
    {                                                  // ---- nbr ----
        int t = (b - segBlocks) * 256 + threadIdx.x;
        int pt = t / 27;
        if(pt >= n) return;
        int d = t - pt * 27;
        if(d == 13) return;
        int4 c = ((const int4*)coords)[pt];
        int nx = c.x + d / 9 - 1, ny = c.y + (d / 3) % 3 - 1, nz = c.z + d % 3 - 1;
        if(((u32)nx >= 256u) | ((u32)ny >= 256u) | ((u32)nz >= 256u)) return;
        u32 bb = ((u32)nx << 16) | ((u32)ny << 8) | (u32)nz;
        if(!((bm[bb >> 5] >> (bb & 31)) & 1u)) return;
        u32 s = hslot(bb);
        u64 e;
        while((u32)((e = hash[s]) >> 32) != bb) s = (s + 1) & HMASK;
        u32 slot = atomicAdd(&nbrcnt[pt], 1u);
        if(slot < 8u) nbrlst[(size_t)pt * 8 + slot] = ((u32)d << 25) | (u32)e;
    }
}

// Software-pipelined final (r10 verbatim: unroll 4 conv loop).
__launch_bounds__(256)
__global__ void k_final(const float* __restrict__ feats,
                        const float* __restrict__ F_input,
                        const float* __restrict__ selfconv,
                        const float* __restrict__ W_pos, const float* __restrict__ alpha,
                        const float* __restrict__ conv_w,
                        const float* __restrict__ ln_w, const float* __restrict__ ln_b,
                        const float* __restrict__ lnl_w, const float* __restrict__ lnl_b,
                        const int* __restrict__ coords,
                        const float* __restrict__ sums, const float* __restrict__ counts,
                        const u32* __restrict__ nbrcnt, const u32* __restrict__ nbrlst,
                        float* __restrict__ out, int n, int nwaves){
    const int lane = threadIdx.x & 63;
    const int wave = (blockIdx.x * blockDim.x + threadIdx.x) >> 6;

    const float wx = W_pos[lane*3+0], wy = W_pos[lane*3+1], wz = W_pos[lane*3+2];
    const float al = alpha[lane];
    const float lnwv = ln_w[lane], lnbv = ln_b[lane];
    const float llwv = lnl_w[lane], llbv = lnl_b[lane];

    int i = wave;
    if(i >= n) return;

    int siA = __builtin_amdgcn_readfirstlane(i);
    int4 cA = ((const int4*)coords)[siA];
    int segA = ((cA.x >> 3) << 10) | ((cA.y >> 3) << 5) | (cA.z >> 3);
    const float* spA = sums + (size_t)segA * 192;
    float s0A = spA[lane], s1A = spA[64+lane], s2A = spA[128+lane];
    float cntA = counts[segA];
    float FA = F_input[(size_t)siA*64 + lane];
    float ScA = selfconv[(size_t)siA*64 + lane];
    u32 ncA = nbrcnt[siA];
    u32 e0A = nbrlst[(size_t)siA*8];

    for(; i < n; ){
        const int inext = i + nwaves;
        const bool hB = inext < n;
        int siB = 0; int4 cB = cA; float s0B=0,s1B=0,s2B=0,cntB=0,FB=0,ScB=0;
        u32 ncB = 0, e0B = 0;
        if(hB){
            siB = __builtin_amdgcn_readfirstlane(inext);
            cB = ((const int4*)coords)[siB];
            int segB = ((cB.x >> 3) << 10) | ((cB.y >> 3) << 5) | (cB.z >> 3);
            const float* spB = sums + (size_t)segB * 192;
            s0B = spB[lane]; s1B = spB[64+lane]; s2B = spB[128+lane];
            cntB = counts[segB];
            FB = F_input[(size_t)siB*64 + lane];
            ScB = selfconv[(size_t)siB*64 + lane];
            ncB = nbrcnt[siB];
            e0B = nbrlst[(size_t)siB*8];
        }

        // ---- compute A ----
        float pos = ((float)cA.x*wx + (float)cA.y*wy + (float)cA.z*wz) * al;
        float sn = __sinf(pos), cs = __cosf(pos);
        float inv = 1.f / fmaxf(cntA, 1.f);
        float newF = fmaf(s0A*inv, cs, fmaf(s1A*inv, sn, s2A*inv - FA*pos));
        float local = ScA;

        u32 cc = ncA > 8u ? 8u : ncA;
        if(cc){
            u32 e = e0A;
            u32 c2 = 0;
            for(;;){
                u32 k = e >> 25, pi = e & 0x1FFFFFFu;
                const float4* gv = (const float4*)(feats + (size_t)pi * 64);
                const float* cw = conv_w + (size_t)k * 4096;
#pragma unroll 4
                for(int q = 0; q < 16; ++q){
                    float4 g = gv[q];
                    local = fmaf(g.x, cw[(4*q    )*64 + lane], local);
                    local = fmaf(g.y, cw[(4*q + 1)*64 + lane], local);
                    local = fmaf(g.z, cw[(4*q + 2)*64 + lane], local);
                    local = fmaf(g.w, cw[(4*q + 3)*64 + lane], local);
                }
                if(++c2 >= cc) break;
                e = nbrlst[(size_t)siA*8 + c2];
            }
        }

        float m1 = wave_sum(newF) * (1.f/64.f);
        float t1 = newF - m1;
        float v1 = wave_sum(t1*t1) * (1.f/64.f);
        float a1 = t1 * rsqrtf(v1 + EPSV) * lnwv + lnbv;

        float m2 = wave_sum(local) * (1.f/64.f);
        float t2 = local - m2;
        float v2 = wave_sum(t2*t2) * (1.f/64.f);
        float a2 = t2 * rsqrtf(v2 + EPSV) * llwv + llbv;

        out[(size_t)siA*64 + lane] = fmaxf(a1 + a2, 0.f);

        i = inext;
        if(hB){
            siA = siB; cA = cB;
            s0A = s0B; s1A = s1B; s2A = s2B; cntA = cntB;
            FA = FB; ScA = ScB; ncA = ncB; e0A = e0B;
        }
    }
}

extern "C" void kernel_launch(void* const* d_in, const int* in_sizes, int n_in,
                              void* d_out, int out_size, void* d_ws, size_t ws_size,
                              hipStream_t stream) {
    (void)n_in; (void)out_size; (void)ws_size;
    const float* feats    = (const float*)d_in[0];
    const float* W_pre    = (const float*)d_in[1];
    const float* ln_pre_w = (const float*)d_in[2];
    const float* ln_pre_b = (const float*)d_in[3];
    const float* W_pos    = (const float*)d_in[4];
    const float* alpha    = (const float*)d_in[5];
    const float* conv_w   = (const float*)d_in[6];
    const float* ln_w     = (const float*)d_in[7];
    const float* ln_b     = (const float*)d_in[8];
    const float* lnl_w    = (const float*)d_in[9];
    const float* lnl_b    = (const float*)d_in[10];
    const int*   coords   = (const int*)d_in[11];

    const int n = in_sizes[0] / 64;

    char* ws = (char*)d_ws;
    size_t o = 0;
    u64*   hash    = (u64*)(ws + o);   o += (size_t)HSIZE * 8;          // 4,194,304
    size_t zoff    = o;
    u32*   bm      = (u32*)(ws + o);   o += 2097152;                    // 2MB bitmap
    u32*   nbrcnt  = (u32*)(ws + o);   o += ((size_t)n*4 + 255) & ~(size_t)255;
    size_t zspan   = o - zoff;
    float* sums    = (float*)(ws + o); o += 25165824;                   // written by seg (no memset)
    float* counts  = (float*)(ws + o); o += 131072;                     // written by seg
    u32*   nbrlst  = (u32*)(ws + o);   o += (size_t)n * 32;             // 8 slots/pt
    float* F_input = (float*)(ws + o); o += (size_t)n * 256;
    float* selfconv= (float*)(ws + o); o += (size_t)n * 256;

    hipMemsetAsync(hash, 0xFF, (size_t)HSIZE * 8, stream);
    hipMemsetAsync(ws + zoff, 0, zspan, stream);

    k_scatter<<<(n + 255)/256, 256, 0, stream>>>(coords, hash, bm, n);

    const int pBlocks = 1024;                         // 4096 waves per role
    k_prew<<<2*pBlocks, 256, 0, stream>>>(feats, W_pre, conv_w, ln_pre_w, ln_pre_b,
                                          F_input, selfconv, n, pBlocks);

    const int segBlocks = 8192;                       // 32768 segments / 4
    const int nbrBlocks = (n*27 + 255) / 256;
    mega2<<<segBlocks + nbrBlocks, 256, 0, stream>>>(F_input, W_pos, alpha, coords,
                                                     hash, bm, sums, counts,
                                                     nbrcnt, nbrlst, n, segBlocks);

    k_final<<<2048, 256, 0, stream>>>(feats, F_input, selfconv, W_pos, alpha, conv_w,
                                      ln_w, ln_b, lnl_w, lnl_b, coords,
                                      sums, counts, nbrcnt, nbrlst,
                                      (float*)d_out, n, 8192);
}

// Round 12
// 294.732 us; speedup vs baseline: 1.0760x; 1.0760x over previous
//
#include <hip/hip_runtime.h>

// ELKUNet forward on MI355X — round 12. f32 device tensors (proven r1/r2/r4/r5).
// Residency saga: r7 (dual arrays, VGPR 72), r10 (role merge, VGPR 40), r11
// (isomorphic merge + launch_bounds(256,4), VGPR 64) ALL demoted the 64-float
// weight array to per-point cache reloads (FETCH = 2x feats is the tell).
// Indexed local arrays give regalloc a scratch escape hatch. Fix: weights as
// 16 NAMED float4 variables (SROA -> named scalars must be allocated), one
// role per kernel, __launch_bounds__(256,2) (VGPR cap 256, no pressure).
// Back half (scatter, mega2 = seg||nbr, k_final unroll-4) = r10 verbatim
// (~99us proven).

typedef unsigned int u32;
typedef unsigned long long u64;

#define EPSV 1e-6f
#define HBITS 19
#define HSIZE (1u << HBITS)
#define HMASK (HSIZE - 1u)

template<int C,int R> __device__ __forceinline__ float dpp_add(float x){
    int y = __builtin_amdgcn_update_dpp(0, __float_as_int(x), C, R, 0xf, true);
    return x + __int_as_float(y);
}
// full 64-lane sum broadcast to all lanes; pure VALU + 1 readlane.
__device__ __forceinline__ float wave_sum(float x){
    x = dpp_add<0xB1,0xF>(x);   // xor 1
    x = dpp_add<0x4E,0xF>(x);   // xor 2
    x = dpp_add<0x141,0xF>(x);  // xor 4
    x = dpp_add<0x140,0xF>(x);  // xor 8
    x = dpp_add<0x142,0xA>(x);  // row_bcast:15
    x = dpp_add<0x143,0xC>(x);  // row_bcast:31
    return __int_as_float(__builtin_amdgcn_readlane(__float_as_int(x), 63));
}

__device__ __forceinline__ u32 hslot(u32 b){ return (b * 0x9E3779B1u) >> (32 - HBITS); }

__global__ void k_scatter(const int* __restrict__ coords, u64* __restrict__ hash,
                          u32* __restrict__ bm, int n){
    int i = blockIdx.x * blockDim.x + threadIdx.x;
    if(i < n){
        int4 c = ((const int4*)coords)[i];
        u32 b = ((u32)c.x << 16) | ((u32)c.y << 8) | (u32)c.z;
        atomicOr(&bm[b >> 5], 1u << (b & 31));
        u64 entry = ((u64)b << 32) | (u32)i;
        u32 s = hslot(b);
        while(atomicCAS(&hash[s], ~0ull, entry) != ~0ull) s = (s + 1) & HMASK;
    }
}

#define MV(f, wq) { a0 = fmaf((f).x, (wq).x, a0); a1 = fmaf((f).y, (wq).y, a1); \
                    a2 = fmaf((f).z, (wq).z, a2); a3 = fmaf((f).w, (wq).w, a3); }

// F_input = LN(feats @ W_pre^T). Weights in 16 NAMED float4 registers.
__launch_bounds__(256, 2)
__global__ void k_pre1(const float* __restrict__ feats, const float* __restrict__ W_pre,
                       const float* __restrict__ lnw, const float* __restrict__ lnb,
                       float* __restrict__ F_input, int n, int nwaves){
    const int lane = threadIdx.x & 63;
    const int wave = (blockIdx.x * blockDim.x + threadIdx.x) >> 6;

    const float4* wr = (const float4*)(W_pre + (size_t)lane * 64);
    float4 w0 = wr[0],  w1 = wr[1],  w2 = wr[2],  w3 = wr[3];
    float4 w4 = wr[4],  w5 = wr[5],  w6 = wr[6],  w7 = wr[7];
    float4 w8 = wr[8],  w9 = wr[9],  wA = wr[10], wB = wr[11];
    float4 wC = wr[12], wD = wr[13], wE = wr[14], wF = wr[15];
    const float lw = lnw[lane], lb = lnb[lane];

    for(int i = wave; i < n; i += nwaves){
        const int si = __builtin_amdgcn_readfirstlane(i);
        const float4* fr = (const float4*)(feats + (size_t)si * 64);
        float a0=0.f, a1=0.f, a2=0.f, a3=0.f;
        MV(fr[0],  w0)  MV(fr[1],  w1)  MV(fr[2],  w2)  MV(fr[3],  w3)
        MV(fr[4],  w4)  MV(fr[5],  w5)  MV(fr[6],  w6)  MV(fr[7],  w7)
        MV(fr[8],  w8)  MV(fr[9],  w9)  MV(fr[10], wA)  MV(fr[11], wB)
        MV(fr[12], wC)  MV(fr[13], wD)  MV(fr[14], wE)  MV(fr[15], wF)
        float acc = (a0 + a1) + (a2 + a3);
        float m = wave_sum(acc) * (1.f/64.f);
        float t = acc - m;
        float v = wave_sum(t*t) * (1.f/64.f);
        F_input[(size_t)si*64 + lane] = t * rsqrtf(v + EPSV) * lw + lb;
    }
}

// selfconv = feats @ conv_w[13]. Weights in 16 NAMED float4 registers.
__launch_bounds__(256, 2)
__global__ void k_pre2(const float* __restrict__ feats, const float* __restrict__ conv_w,
                       float* __restrict__ selfconv, int n, int nwaves){
    const int lane = threadIdx.x & 63;
    const int wave = (blockIdx.x * blockDim.x + threadIdx.x) >> 6;

    const float* cw = conv_w + 13*64*64 + lane;          // cw[j*64] = conv_w[13][j][lane]
#define LW(q) make_float4(cw[(4*(q))*64], cw[(4*(q)+1)*64], cw[(4*(q)+2)*64], cw[(4*(q)+3)*64])
    float4 w0 = LW(0),  w1 = LW(1),  w2 = LW(2),  w3 = LW(3);
    float4 w4 = LW(4),  w5 = LW(5),  w6 = LW(6),  w7 = LW(7);
    float4 w8 = LW(8),  w9 = LW(9),  wA = LW(10), wB = LW(11);
    float4 wC = LW(12), wD = LW(13), wE = LW(14), wF = LW(15);
#undef LW

    for(int i = wave; i < n; i += nwaves){
        const int si = __builtin_amdgcn_readfirstlane(i);
        const float4* fr = (const float4*)(feats + (size_t)si * 64);
        float a0=0.f, a1=0.f, a2=0.f, a3=0.f;
        MV(fr[0],  w0)  MV(fr[1],  w1)  MV(fr[2],  w2)  MV(fr[3],  w3)
        MV(fr[4],  w4)  MV(fr[5],  w5)  MV(fr[6],  w6)  MV(fr[7],  w7)
        MV(fr[8],  w8)  MV(fr[9],  w9)  MV(fr[10], wA)  MV(fr[11], wB)
        MV(fr[12], wC)  MV(fr[13], wD)  MV(fr[14], wE)  MV(fr[15], wF)
        selfconv[(size_t)si*64 + lane] = (a0 + a1) + (a2 + a3);
    }
}

// ---- mega2: seg || nbr (r10 verbatim) ------------------------------------
__launch_bounds__(256)
__global__ void mega2(const float* __restrict__ F_input,
                      const float* __restrict__ W_pos, const float* __restrict__ alpha,
                      const int* __restrict__ coords,
                      const u64* __restrict__ hash, const u32* __restrict__ bm,
                      float* __restrict__ sums, float* __restrict__ counts,
                      u32* __restrict__ nbrcnt, u32* __restrict__ nbrlst,
                      int n, int segBlocks){
    const int b = blockIdx.x;
    const int lane = threadIdx.x & 63;

    if(b < segBlocks){                                 // ---- seg ----
        const u64* bm64 = (const u64*)bm;
        const int seg  = (b << 2) + (threadIdx.x >> 6);
        const int cx = seg >> 10, cy = (seg >> 5) & 31, cz = seg & 31;
        const int px = (cx << 3) + (lane >> 3), py = (cy << 3) + (lane & 7);
        u64 w = bm64[((size_t)px << 10) | ((u32)py << 2) | (u32)(cz >> 3)];
        u32 o8 = (u32)(w >> ((cz & 7) * 8)) & 0xffu;
        float cnt = wave_sum((float)__popc(o8));

        const float wx = W_pos[lane*3+0], wy = W_pos[lane*3+1], wz = W_pos[lane*3+2];
        const float al = alpha[lane];
        float aC = 0.f, aS = 0.f, aL = 0.f;
        while(__ballot(o8 != 0u)){
            int myz = 0, pid = -1;
            if(o8){
                int dz = __ffs(o8) - 1; o8 &= o8 - 1;
                myz = (cz << 3) + dz;
                u32 bb = ((u32)px << 16) | ((u32)py << 8) | (u32)myz;
                u32 s = hslot(bb); u64 e;
                while((u32)((e = hash[s]) >> 32) != bb) s = (s + 1) & HMASK;
                pid = (int)(u32)e;
            }
            u64 mm = __ballot(pid >= 0);
            while(mm){
                int l = __ffsll(mm) - 1; mm &= mm - 1;
                int p  = __builtin_amdgcn_readlane(pid, l);
                int pz = __builtin_amdgcn_readlane(myz, l);
                int qx = (cx << 3) + (l >> 3), qy = (cy << 3) + (l & 7);
                float F = F_input[(size_t)p * 64 + lane];
                float pos = ((float)qx*wx + (float)qy*wy + (float)pz*wz) * al;
                aC = fmaf(F, __cosf(pos), aC);
                aS = fmaf(F, __sinf(pos), aS);
                aL = fmaf(F, pos, aL);
            }
        }
        float* sp = sums + (size_t)seg * 192;
        sp[lane] = aC; sp[64 + lane] = aS; sp[128 + lane] = aL;
        if(lane == 0) counts[seg] = cnt;
        return;
    }
    {                                                  // ---- nbr ----
        int t = (b - segBlocks) * 256 + threadIdx.x;
        int pt = t / 27;
        if(pt >= n) return;
        int d = t - pt * 27;
        if(d == 13) return;
        int4 c = ((const int4*)coords)[pt];
        int nx = c.x + d / 9 - 1, ny = c.y + (d / 3) % 3 - 1, nz = c.z + d % 3 - 1;
        if(((u32)nx >= 256u) | ((u32)ny >= 256u) | ((u32)nz >= 256u)) return;
        u32 bb = ((u32)nx << 16) | ((u32)ny << 8) | (u32)nz;
        if(!((bm[bb >> 5] >> (bb & 31)) & 1u)) return;
        u32 s = hslot(bb);
        u64 e;
        while((u32)((e = hash[s]) >> 32) != bb) s = (s + 1) & HMASK;
        u32 slot = atomicAdd(&nbrcnt[pt], 1u);
        if(slot < 8u) nbrlst[(size_t)pt * 8 + slot] = ((u32)d << 25) | (u32)e;
    }
}

// Software-pipelined final (r10 verbatim: unroll 4 conv loop).
__launch_bounds__(256)
__global__ void k_final(const float* __restrict__ feats,
                        const float* __restrict__ F_input,
                        const float* __restrict__ selfconv,
                        const float* __restrict__ W_pos, const float* __restrict__ alpha,
                        const float* __restrict__ conv_w,
                        const float* __restrict__ ln_w, const float* __restrict__ ln_b,
                        const float* __restrict__ lnl_w, const float* __restrict__ lnl_b,
                        const int* __restrict__ coords,
                        const float* __restrict__ sums, const float* __restrict__ counts,
                        const u32* __restrict__ nbrcnt, const u32* __restrict__ nbrlst,
                        float* __restrict__ out, int n, int nwaves){
    const int lane = threadIdx.x & 63;
    const int wave = (blockIdx.x * blockDim.x + threadIdx.x) >> 6;

    const float wx = W_pos[lane*3+0], wy = W_pos[lane*3+1], wz = W_pos[lane*3+2];
    const float al = alpha[lane];
    const float lnwv = ln_w[lane], lnbv = ln_b[lane];
    const float llwv = lnl_w[lane], llbv = lnl_b[lane];

    int i = wave;
    if(i >= n) return;

    int siA = __builtin_amdgcn_readfirstlane(i);
    int4 cA = ((const int4*)coords)[siA];
    int segA = ((cA.x >> 3) << 10) | ((cA.y >> 3) << 5) | (cA.z >> 3);
    const float* spA = sums + (size_t)segA * 192;
    float s0A = spA[lane], s1A = spA[64+lane], s2A = spA[128+lane];
    float cntA = counts[segA];
    float FA = F_input[(size_t)siA*64 + lane];
    float ScA = selfconv[(size_t)siA*64 + lane];
    u32 ncA = nbrcnt[siA];
    u32 e0A = nbrlst[(size_t)siA*8];

    for(; i < n; ){
        const int inext = i + nwaves;
        const bool hB = inext < n;
        int siB = 0; int4 cB = cA; float s0B=0,s1B=0,s2B=0,cntB=0,FB=0,ScB=0;
        u32 ncB = 0, e0B = 0;
        if(hB){
            siB = __builtin_amdgcn_readfirstlane(inext);
            cB = ((const int4*)coords)[siB];
            int segB = ((cB.x >> 3) << 10) | ((cB.y >> 3) << 5) | (cB.z >> 3);
            const float* spB = sums + (size_t)segB * 192;
            s0B = spB[lane]; s1B = spB[64+lane]; s2B = spB[128+lane];
            cntB = counts[segB];
            FB = F_input[(size_t)siB*64 + lane];
            ScB = selfconv[(size_t)siB*64 + lane];
            ncB = nbrcnt[siB];
            e0B = nbrlst[(size_t)siB*8];
        }

        // ---- compute A ----
        float pos = ((float)cA.x*wx + (float)cA.y*wy + (float)cA.z*wz) * al;
        float sn = __sinf(pos), cs = __cosf(pos);
        float inv = 1.f / fmaxf(cntA, 1.f);
        float newF = fmaf(s0A*inv, cs, fmaf(s1A*inv, sn, s2A*inv - FA*pos));
        float local = ScA;

        u32 cc = ncA > 8u ? 8u : ncA;
        if(cc){
            u32 e = e0A;
            u32 c2 = 0;
            for(;;){
                u32 k = e >> 25, pi = e & 0x1FFFFFFu;
                const float4* gv = (const float4*)(feats + (size_t)pi * 64);
                const float* cw = conv_w + (size_t)k * 4096;
#pragma unroll 4
                for(int q = 0; q < 16; ++q){
                    float4 g = gv[q];
                    local = fmaf(g.x, cw[(4*q    )*64 + lane], local);
                    local = fmaf(g.y, cw[(4*q + 1)*64 + lane], local);
                    local = fmaf(g.z, cw[(4*q + 2)*64 + lane], local);
                    local = fmaf(g.w, cw[(4*q + 3)*64 + lane], local);
                }
                if(++c2 >= cc) break;
                e = nbrlst[(size_t)siA*8 + c2];
            }
        }

        float m1 = wave_sum(newF) * (1.f/64.f);
        float t1 = newF - m1;
        float v1 = wave_sum(t1*t1) * (1.f/64.f);
        float a1 = t1 * rsqrtf(v1 + EPSV) * lnwv + lnbv;

        float m2 = wave_sum(local) * (1.f/64.f);
        float t2 = local - m2;
        float v2 = wave_sum(t2*t2) * (1.f/64.f);
        float a2 = t2 * rsqrtf(v2 + EPSV) * llwv + llbv;

        out[(size_t)siA*64 + lane] = fmaxf(a1 + a2, 0.f);

        i = inext;
        if(hB){
            siA = siB; cA = cB;
            s0A = s0B; s1A = s1B; s2A = s2B; cntA = cntB;
            FA = FB; ScA = ScB; ncA = ncB; e0A = e0B;
        }
    }
}

extern "C" void kernel_launch(void* const* d_in, const int* in_sizes, int n_in,
                              void* d_out, int out_size, void* d_ws, size_t ws_size,
                              hipStream_t stream) {
    (void)n_in; (void)out_size; (void)ws_size;
    const float* feats    = (const float*)d_in[0];
    const float* W_pre    = (const float*)d_in[1];
    const float* ln_pre_w = (const float*)d_in[2];
    const float* ln_pre_b = (const float*)d_in[3];
    const float* W_pos    = (const float*)d_in[4];
    const float* alpha    = (const float*)d_in[5];
    const float* conv_w   = (const float*)d_in[6];
    const float* ln_w     = (const float*)d_in[7];
    const float* ln_b     = (const float*)d_in[8];
    const float* lnl_w    = (const float*)d_in[9];
    const float* lnl_b    = (const float*)d_in[10];
    const int*   coords   = (const int*)d_in[11];

    const int n = in_sizes[0] / 64;

    char* ws = (char*)d_ws;
    size_t o = 0;
    u64*   hash    = (u64*)(ws + o);   o += (size_t)HSIZE * 8;          // 4,194,304
    size_t zoff    = o;
    u32*   bm      = (u32*)(ws + o);   o += 2097152;                    // 2MB bitmap
    u32*   nbrcnt  = (u32*)(ws + o);   o += ((size_t)n*4 + 255) & ~(size_t)255;
    size_t zspan   = o - zoff;
    float* sums    = (float*)(ws + o); o += 25165824;                   // written by seg (no memset)
    float* counts  = (float*)(ws + o); o += 131072;                     // written by seg
    u32*   nbrlst  = (u32*)(ws + o);   o += (size_t)n * 32;             // 8 slots/pt
    float* F_input = (float*)(ws + o); o += (size_t)n * 256;
    float* selfconv= (float*)(ws + o); o += (size_t)n * 256;

    hipMemsetAsync(hash, 0xFF, (size_t)HSIZE * 8, stream);
    hipMemsetAsync(ws + zoff, 0, zspan, stream);

    k_scatter<<<(n + 255)/256, 256, 0, stream>>>(coords, hash, bm, n);
    k_pre1<<<2048, 256, 0, stream>>>(feats, W_pre, ln_pre_w, ln_pre_b, F_input, n, 8192);
    k_pre2<<<2048, 256, 0, stream>>>(feats, conv_w, selfconv, n, 8192);

    const int segBlocks = 8192;                       // 32768 segments / 4
    const int nbrBlocks = (n*27 + 255) / 256;
    mega2<<<segBlocks + nbrBlocks, 256, 0, stream>>>(F_input, W_pos, alpha, coords,
                                                     hash, bm, sums, counts,
                                                     nbrcnt, nbrlst, n, segBlocks);

    k_final<<<2048, 256, 0, stream>>>(feats, F_input, selfconv, W_pos, alpha, conv_w,
                                      ln_w, ln_b, lnl_w, lnl_b, coords,
                                      sums, counts, nbrcnt, nbrlst,
                                      (float*)d_out, n, 8192);
}

// Round 13
// 241.516 us; speedup vs baseline: 1.3131x; 1.2203x over previous
//
#include <hip/hip_runtime.h>

// ELKUNet forward on MI355X — round 13. f32 device tensors (proven r1/r2/r4/r5).
// Pipeline: memset -> k_scatter (hash+bitmap) -> k_preB (dual matvec, weights
// in 32 NAMED float4 regs, r12-proven residency recipe) -> k_segfinal
// (1 wave/segment: pass1 = enumerate+segment sums in regs; pass2 = newF
// combine + inline 9-lane neighbor probe + conv + 2 LNs + out).
// vs r12: sums/counts/nbrcnt/nbrlst buffers gone, nbr+final launches gone,
// feats read once in pre. r6's fused failure doesn't apply: no matvec on the
// segment-serial chain, no LDS (full occupancy), conv is rare (~0.31/pt).

typedef unsigned int u32;
typedef unsigned long long u64;

#define EPSV 1e-6f
#define HBITS 19
#define HSIZE (1u << HBITS)
#define HMASK (HSIZE - 1u)

template<int C,int R> __device__ __forceinline__ float dpp_add(float x){
    int y = __builtin_amdgcn_update_dpp(0, __float_as_int(x), C, R, 0xf, true);
    return x + __int_as_float(y);
}
// full 64-lane sum broadcast to all lanes; pure VALU + 1 readlane.
__device__ __forceinline__ float wave_sum(float x){
    x = dpp_add<0xB1,0xF>(x);   // xor 1
    x = dpp_add<0x4E,0xF>(x);   // xor 2
    x = dpp_add<0x141,0xF>(x);  // xor 4
    x = dpp_add<0x140,0xF>(x);  // xor 8
    x = dpp_add<0x142,0xA>(x);  // row_bcast:15
    x = dpp_add<0x143,0xC>(x);  // row_bcast:31
    return __int_as_float(__builtin_amdgcn_readlane(__float_as_int(x), 63));
}

__device__ __forceinline__ u32 hslot(u32 b){ return (b * 0x9E3779B1u) >> (32 - HBITS); }

__global__ void k_scatter(const int* __restrict__ coords, u64* __restrict__ hash,
                          u32* __restrict__ bm, int n){
    int i = blockIdx.x * blockDim.x + threadIdx.x;
    if(i < n){
        int4 c = ((const int4*)coords)[i];
        u32 b = ((u32)c.x << 16) | ((u32)c.y << 8) | (u32)c.z;
        atomicOr(&bm[b >> 5], 1u << (b & 31));
        u64 entry = ((u64)b << 32) | (u32)i;
        u32 s = hslot(b);
        while(atomicCAS(&hash[s], ~0ull, entry) != ~0ull) s = (s + 1) & HMASK;
    }
}

#define MV2(f, wq, vq) { float4 _f = (f); \
    a0 = fmaf(_f.x, (wq).x, a0); a1 = fmaf(_f.y, (wq).y, a1); \
    a2 = fmaf(_f.z, (wq).z, a2); a3 = fmaf(_f.w, (wq).w, a3); \
    s0 = fmaf(_f.x, (vq).x, s0); s1 = fmaf(_f.y, (vq).y, s1); \
    s2 = fmaf(_f.z, (vq).z, s2); s3 = fmaf(_f.w, (vq).w, s3); }

// F_input = LN(feats @ W_pre^T); selfconv = feats @ conv_w[13].
// Both weight sets in 32 NAMED float4 registers (r12-proven residency).
__launch_bounds__(256, 2)
__global__ void k_preB(const float* __restrict__ feats, const float* __restrict__ W_pre,
                       const float* __restrict__ conv_w,
                       const float* __restrict__ lnw, const float* __restrict__ lnb,
                       float* __restrict__ F_input, float* __restrict__ selfconv,
                       int n, int nwaves){
    const int lane = threadIdx.x & 63;
    const int wave = (blockIdx.x * blockDim.x + threadIdx.x) >> 6;

    const float4* wr = (const float4*)(W_pre + (size_t)lane * 64);
    float4 w0 = wr[0],  w1 = wr[1],  w2 = wr[2],  w3 = wr[3];
    float4 w4 = wr[4],  w5 = wr[5],  w6 = wr[6],  w7 = wr[7];
    float4 w8 = wr[8],  w9 = wr[9],  wA = wr[10], wB = wr[11];
    float4 wC = wr[12], wD = wr[13], wE = wr[14], wF = wr[15];

    const float* cwp = conv_w + 13*64*64 + lane;     // cwp[j*64] = conv_w[13][j][lane]
#define LW(q) make_float4(cwp[(4*(q))*64], cwp[(4*(q)+1)*64], cwp[(4*(q)+2)*64], cwp[(4*(q)+3)*64])
    float4 v0 = LW(0),  v1 = LW(1),  v2 = LW(2),  v3 = LW(3);
    float4 v4 = LW(4),  v5 = LW(5),  v6 = LW(6),  v7 = LW(7);
    float4 v8 = LW(8),  v9 = LW(9),  vA = LW(10), vB = LW(11);
    float4 vC = LW(12), vD = LW(13), vE = LW(14), vF = LW(15);
#undef LW

    const float lw = lnw[lane], lb = lnb[lane];

    for(int i = wave; i < n; i += nwaves){
        const int si = __builtin_amdgcn_readfirstlane(i);
        const float4* fr = (const float4*)(feats + (size_t)si * 64);
        float a0=0.f, a1=0.f, a2=0.f, a3=0.f;
        float s0=0.f, s1=0.f, s2=0.f, s3=0.f;
        MV2(fr[0],  w0, v0)  MV2(fr[1],  w1, v1)  MV2(fr[2],  w2, v2)  MV2(fr[3],  w3, v3)
        MV2(fr[4],  w4, v4)  MV2(fr[5],  w5, v5)  MV2(fr[6],  w6, v6)  MV2(fr[7],  w7, v7)
        MV2(fr[8],  w8, v8)  MV2(fr[9],  w9, v9)  MV2(fr[10], wA, vA)  MV2(fr[11], wB, vB)
        MV2(fr[12], wC, vC)  MV2(fr[13], wD, vD)  MV2(fr[14], wE, vE)  MV2(fr[15], wF, vF)
        float acc = (a0 + a1) + (a2 + a3);
        float m = wave_sum(acc) * (1.f/64.f);
        float t = acc - m;
        float v = wave_sum(t*t) * (1.f/64.f);
        F_input[(size_t)si*64 + lane] = t * rsqrtf(v + EPSV) * lw + lb;
        selfconv[(size_t)si*64 + lane] = (s0 + s1) + (s2 + s3);
    }
}

// 1 wave = 1 segment. Pass1: enumerate own points (bitmap+hash), accumulate
// segment sums in registers. Pass2: re-enumerate (L1-hot), per point: newF
// combine + inline 9-lane neighbor probe + rare conv + 2 LNs + relu + out.
__launch_bounds__(256)
__global__ void k_segfinal(const float* __restrict__ F_input,
                           const float* __restrict__ selfconv,
                           const float* __restrict__ feats,
                           const float* __restrict__ W_pos, const float* __restrict__ alpha,
                           const float* __restrict__ conv_w,
                           const float* __restrict__ ln_w, const float* __restrict__ ln_b,
                           const float* __restrict__ lnl_w, const float* __restrict__ lnl_b,
                           const u64* __restrict__ hash, const u32* __restrict__ bm,
                           float* __restrict__ out){
    const u64* bm64 = (const u64*)bm;
    const int lane = threadIdx.x & 63;
    const int seg  = (blockIdx.x << 2) + (threadIdx.x >> 6);
    const int cx = seg >> 10, cy = (seg >> 5) & 31, cz = seg & 31;

    const int px = (cx << 3) + (lane >> 3), py = (cy << 3) + (lane & 7);
    u64 w = bm64[((size_t)px << 10) | ((u32)py << 2) | (u32)(cz >> 3)];
    u32 o8 = (u32)(w >> ((cz & 7) * 8)) & 0xffu;
    if(__ballot(o8 != 0u) == 0ull) return;

    const float wx = W_pos[lane*3+0], wy = W_pos[lane*3+1], wz = W_pos[lane*3+2];
    const float al = alpha[lane];

    // ---- pass 1: segment sums in registers ----
    float aC = 0.f, aS = 0.f, aL = 0.f;
    u32 t8 = o8;
    while(__ballot(t8 != 0u)){
        int myz = 0, pid = -1;
        if(t8){
            int dz = __ffs(t8) - 1; t8 &= t8 - 1;
            myz = (cz << 3) + dz;
            u32 b = ((u32)px << 16) | ((u32)py << 8) | (u32)myz;
            u32 s = hslot(b); u64 e;
            while((u32)((e = hash[s]) >> 32) != b) s = (s + 1) & HMASK;
            pid = (int)(u32)e;
        }
        u64 mm = __ballot(pid >= 0);
        while(mm){
            int l = __ffsll(mm) - 1; mm &= mm - 1;
            int p  = __builtin_amdgcn_readlane(pid, l);
            int pz = __builtin_amdgcn_readlane(myz, l);
            int qx = (cx << 3) + (l >> 3), qy = (cy << 3) + (l & 7);
            float F = F_input[(size_t)p * 64 + lane];
            float pos = ((float)qx*wx + (float)qy*wy + (float)pz*wz) * al;
            aC = fmaf(F, __cosf(pos), aC);
            aS = fmaf(F, __sinf(pos), aS);
            aL = fmaf(F, pos, aL);
        }
    }
    const float inv = 1.f / wave_sum((float)__popc(o8));
    const float vCv = aC * inv, vSv = aS * inv, vLv = aL * inv;
    const float lnwv = ln_w[lane], lnbv = ln_b[lane];
    const float llwv = lnl_w[lane], llbv = lnl_b[lane];

    // ---- pass 2: per point finale (hash/F re-probes are L1-hot) ----
    t8 = o8;
    while(__ballot(t8 != 0u)){
        int myz = 0, pid = -1;
        if(t8){
            int dz = __ffs(t8) - 1; t8 &= t8 - 1;
            myz = (cz << 3) + dz;
            u32 b = ((u32)px << 16) | ((u32)py << 8) | (u32)myz;
            u32 s = hslot(b); u64 e;
            while((u32)((e = hash[s]) >> 32) != b) s = (s + 1) & HMASK;
            pid = (int)(u32)e;
        }
        u64 mm = __ballot(pid >= 0);
        while(mm){
            int l = __ffsll(mm) - 1; mm &= mm - 1;
            int p  = __builtin_amdgcn_readlane(pid, l);
            int pz = __builtin_amdgcn_readlane(myz, l);
            int qx = (cx << 3) + (l >> 3), qy = (cy << 3) + (l & 7);

            float F  = F_input[(size_t)p * 64 + lane];     // L1-hot
            float Sc = selfconv[(size_t)p * 64 + lane];

            // neighbor probe: lanes 0..8 cover (dx,dy); 3 z-bits each
            u32 m3 = 0;
            if(lane < 9){
                int nx = qx + lane/3 - 1, ny = qy + lane%3 - 1;
                if(((u32)nx < 256u) && ((u32)ny < 256u)){
                    const u64* wp = bm64 + (((size_t)nx << 10) | ((u32)ny << 2));
                    int zb = pz & 63;
                    if(zb >= 1 && zb <= 62){
                        u64 ww = wp[pz >> 6];
                        m3 = (u32)((ww >> (zb - 1)) & 7ull);
                    } else {
#pragma unroll
                        for(int t = 0; t < 3; ++t){
                            int zz = pz + t - 1;
                            if((u32)zz < 256u){
                                u64 ww = wp[zz >> 6];
                                m3 |= (u32)((ww >> (zz & 63)) & 1ull) << t;
                            }
                        }
                    }
                }
            }
            u64 b0 = __ballot(m3 & 1u);
            u64 b1 = __ballot(m3 & 2u) & ~(1ull << 4);   // drop self (l2=4, dz=0)
            u64 b2 = __ballot(m3 & 4u);

            float pos = ((float)qx*wx + (float)qy*wy + (float)pz*wz) * al;
            float sn = __sinf(pos), cs = __cosf(pos);
            float newF = fmaf(vCv, cs, fmaf(vSv, sn, vLv - F*pos));
            float local = Sc;

#pragma unroll
            for(int t = 0; t < 3; ++t){
                u64 mm2 = (t == 0) ? b0 : ((t == 1) ? b1 : b2);
                while(mm2){
                    int l2 = __ffsll(mm2) - 1; mm2 &= mm2 - 1;
                    int nx = qx + l2/3 - 1, ny = qy + l2%3 - 1, nz = pz + t - 1;
                    int k = 3*l2 + t;
                    u32 nb = ((u32)nx << 16) | ((u32)ny << 8) | (u32)nz;
                    u32 s = hslot(nb); u64 e;
                    while((u32)((e = hash[s]) >> 32) != nb) s = (s + 1) & HMASK;
                    const int pin = (int)(u32)e;
                    const float4* gv = (const float4*)(feats + (size_t)pin * 64);
                    const float* cw = conv_w + (size_t)k * 4096;
#pragma unroll 4
                    for(int q = 0; q < 16; ++q){
                        float4 g = gv[q];
                        local = fmaf(g.x, cw[(4*q    )*64 + lane], local);
                        local = fmaf(g.y, cw[(4*q + 1)*64 + lane], local);
                        local = fmaf(g.z, cw[(4*q + 2)*64 + lane], local);
                        local = fmaf(g.w, cw[(4*q + 3)*64 + lane], local);
                    }
                }
            }

            float m1 = wave_sum(newF) * (1.f/64.f);
            float t1 = newF - m1;
            float v1 = wave_sum(t1*t1) * (1.f/64.f);
            float a1 = t1 * rsqrtf(v1 + EPSV) * lnwv + lnbv;

            float m2 = wave_sum(local) * (1.f/64.f);
            float t2 = local - m2;
            float v2 = wave_sum(t2*t2) * (1.f/64.f);
            float a2 = t2 * rsqrtf(v2 + EPSV) * llwv + llbv;

            out[(size_t)p*64 + lane] = fmaxf(a1 + a2, 0.f);
        }
    }
}

extern "C" void kernel_launch(void* const* d_in, const int* in_sizes, int n_in,
                              void* d_out, int out_size, void* d_ws, size_t ws_size,
                              hipStream_t stream) {
    (void)n_in; (void)out_size; (void)ws_size;
    const float* feats    = (const float*)d_in[0];
    const float* W_pre    = (const float*)d_in[1];
    const float* ln_pre_w = (const float*)d_in[2];
    const float* ln_pre_b = (const float*)d_in[3];
    const float* W_pos    = (const float*)d_in[4];
    const float* alpha    = (const float*)d_in[5];
    const float* conv_w   = (const float*)d_in[6];
    const float* ln_w     = (const float*)d_in[7];
    const float* ln_b     = (const float*)d_in[8];
    const float* lnl_w    = (const float*)d_in[9];
    const float* lnl_b    = (const float*)d_in[10];
    const int*   coords   = (const int*)d_in[11];

    const int n = in_sizes[0] / 64;

    char* ws = (char*)d_ws;
    size_t o = 0;
    u64*   hash    = (u64*)(ws + o);   o += (size_t)HSIZE * 8;          // 4,194,304
    u32*   bm      = (u32*)(ws + o);   o += 2097152;                    // 2MB bitmap
    float* F_input = (float*)(ws + o); o += (size_t)n * 256;
    float* selfconv= (float*)(ws + o); o += (size_t)n * 256;

    hipMemsetAsync(hash, 0xFF, (size_t)HSIZE * 8, stream);
    hipMemsetAsync(bm, 0, 2097152, stream);

    k_scatter<<<(n + 255)/256, 256, 0, stream>>>(coords, hash, bm, n);
    k_preB<<<2048, 256, 0, stream>>>(feats, W_pre, conv_w, ln_pre_w, ln_pre_b,
                                     F_input, selfconv, n, 8192);
    k_segfinal<<<8192, 256, 0, stream>>>(F_input, selfconv, feats, W_pos, alpha,
                                         conv_w, ln_w, ln_b, lnl_w, lnl_b,
                                         hash, bm, (float*)d_out);
}